// Round 6
// baseline (461.077 us; speedup 1.0000x reference)
//
#include <hip/hip_runtime.h>
#include <stdint.h>

// SO2MLP: out = so2_linear(rot_act(so2_linear(x,W1)), W2)
// R6: - prep_x fused into so2_gemm staging (reads x directly, rotates, writes
//       swizzled LDS). Grid (l fastest) so 6 sibling blocks share x via L3.
//     - MTILE=128, waves 2(M)x4(N), 2 B-frags/wave in BOTH gemms (each A-read
//       feeds 2 MFMAs, each W-read feeds 2 MFMAs). LDS 128KB, 1 block/CU.
//     - A2 single buffer (chunk=256), 6 barriers/tile.
//     - G stored plain; post_out unchanged. Epilogue via LDS (R3 lesson).

#define LMAX 6
#define NN 20000
#define RIN 256
#define RHID 512
#define ROUT 256
#define MTILE 128            // 64 nodes x 2 components
#define NTILES 313           // 313*128 = 40064 rows
#define MPAD (NTILES*MTILE)

typedef __attribute__((ext_vector_type(8))) short short8;
typedef __attribute__((ext_vector_type(16))) float f32x16;

__device__ __forceinline__ uint16_t f2bf(float f) {
  uint32_t x = __builtin_bit_cast(uint32_t, f);
  x += 0x7fffu + ((x >> 16) & 1u);   // round-to-nearest-even
  return (uint16_t)(x >> 16);
}
__device__ __forceinline__ float bf2f(uint16_t u) {
  return __builtin_bit_cast(float, ((uint32_t)u) << 16);
}

__device__ __forceinline__ f32x16 mfma32(short8 a, short8 b, f32x16 c) {
  return __builtin_amdgcn_mfma_f32_32x32x16_bf16(a, b, c, 0, 0, 0);
}

// 512B-row LDS address with 16B-granule swizzle (verified R4/R5: 0 conflicts)
__device__ __forceinline__ int swz512(int row, int colb) {
  return row * 512 + ((((colb >> 4) ^ row) & 31) << 4) + (colb & 15);
}

// ---------------------------------------------------------------------------
// K1: weights fp32 -> bf16, 32x32x16 B-fragment-linear (verified R4/R5).
// B frag: col = lane&31, k = (lane>>5)*8 + e; (frag,kstep) = 1KB contiguous.
// ---------------------------------------------------------------------------
__global__ void prep_weights(const float* __restrict__ W1, const float* __restrict__ W2,
                             uint16_t* __restrict__ w1f, uint16_t* __restrict__ w2f) {
  int idx = blockIdx.x * 256 + threadIdx.x;
  if (idx >= LMAX * RHID * RIN) return;
  {
    // W1[l][o][i], K=256 -> 16 ksteps; 16 out-frags of 32
    int l = idx / (RHID * RIN);
    int rem = idx - l * (RHID * RIN);
    int o = rem >> 8;
    int i = rem & 255;
    int lane = ((i >> 3) & 1) * 32 + (o & 31);
    size_t dst = (size_t)l * (RHID * RIN) +
                 ((((size_t)(o >> 5) * 16 + (i >> 4)) * 64 + lane) * 8 + (i & 7));
    w1f[dst] = f2bf(W1[idx]);
  }
  {
    // W2[l][o][j], K=512 -> 32 ksteps; 8 out-frags of 32
    int l = idx / (ROUT * RHID);
    int rem = idx - l * (ROUT * RHID);
    int o = rem >> 9;
    int j = rem & 511;
    int lane = ((j >> 3) & 1) * 32 + (o & 31);
    size_t dst = (size_t)l * (ROUT * RHID) +
                 ((((size_t)(o >> 5) * 32 + (j >> 4)) * 64 + lane) * 8 + (j & 7));
    w2f[dst] = f2bf(W2[idx]);
  }
}

// ---------------------------------------------------------------------------
// K2: fused rotate + dual GEMM per (degree, 128-row tile), 32x32x16 MFMA.
// 512 thr = 8 waves = 2(wm) x 4(wn). Per wave: 2 m-frags x 2 n-frags.
// A-frag: row=lane&31, k=(lane>>5)*8+e; C/D: col=lane&31,
// row=(r&3)+8*(r>>2)+4*(lane>>5)  (all verified R4/R5).
// ---------------------------------------------------------------------------
__global__ __launch_bounds__(512, 2) void so2_gemm(
    const float* __restrict__ x,
    const float* __restrict__ rot,
    const uint16_t* __restrict__ w1f,
    const uint16_t* __restrict__ w2f,
    uint16_t* __restrict__ g) {
  __shared__ alignas(16) uint8_t Xs[MTILE * 512];   // 64KB, swizzled
  __shared__ alignas(16) uint8_t A2[MTILE * 512];   // 64KB, swizzled

  const int l = blockIdx.x;            // l fastest: siblings share x via L3
  const int tile = blockIdx.y;
  const int n0 = tile * 64;            // node base (64 nodes per tile)
  const int tid = threadIdx.x;
  const int lane = tid & 63;
  const int wid = tid >> 6;
  const int l31 = lane & 31;
  const int lh = lane >> 5;
  const int wm = wid & 1;              // M half (2 m-frags each)
  const int wn = wid >> 1;             // N quarter (2 n-frags each)

  const uint16_t* w1p = w1f + (size_t)l * (RHID * RIN);
  const uint16_t* w2p = w2f + (size_t)l * (ROUT * RHID);

  // ---- STAGE_X: read x, rotate into local frame, write swizzled Xs ----
  // 64 nodes x 256 i = 16384 (n,i) pairs; 32 per thread; lanes->consecutive i
#pragma unroll 4
  for (int j = 0; j < 32; ++j) {
    int p = j * 512 + tid;
    int nl = p >> 8, i = p & 255;
    int n = n0 + nl;
    int ns = n < NN ? n : NN - 1;
    float c0 = 0.f, c1 = 0.f;
    if (n < NN) {
      const float* xp = x + ((size_t)n * 256 + i) * 12 + l * 2;
      c0 = xp[0]; c1 = xp[1];
    }
    const float4 r4 = *(const float4*)(rot + (size_t)ns * 24 + l * 4); // [m][c]
    float a0 = c0 * r4.x + c1 * r4.z;   // c=0: r00*x0 + r10*x1
    float a1 = c0 * r4.y + c1 * r4.w;   // c=1: r01*x0 + r11*x1
    int r0 = nl * 2;
    *(uint16_t*)(Xs + swz512(r0, i * 2)) = f2bf(a0);
    *(uint16_t*)(Xs + swz512(r0 + 1, i * 2)) = f2bf(a1);
  }
  __syncthreads();

  f32x16 acc1[2][2];   // [mf][fc] G1 chunk accum
  f32x16 acc2[2][2];   // [mf][nf] G2 running accum
#pragma unroll
  for (int a = 0; a < 2; ++a)
#pragma unroll
    for (int b = 0; b < 2; ++b) acc2[a][b] = (f32x16)(0.f);

  auto G1 = [&](int oc) {   // acc1 = Xs(2 mf) @ W1 frags {oc*8+wn*2, +1}
#pragma unroll
    for (int a = 0; a < 2; ++a)
#pragma unroll
      for (int b = 0; b < 2; ++b) acc1[a][b] = (f32x16)(0.f);
    const uint16_t* wb0 = w1p + (size_t)(oc * 8 + wn * 2) * (16 * 64 * 8);
    const uint16_t* wb1 = wb0 + 16 * 64 * 8;
#pragma unroll 4
    for (int ks = 0; ks < 16; ++ks) {
      short8 b0 = *(const short8*)(wb0 + ((size_t)ks * 64 + lane) * 8);
      short8 b1 = *(const short8*)(wb1 + ((size_t)ks * 64 + lane) * 8);
#pragma unroll
      for (int mf = 0; mf < 2; ++mf) {
        short8 a = *(const short8*)(Xs + swz512((wm * 2 + mf) * 32 + l31,
                                                ks * 32 + lh * 16));
        acc1[mf][0] = mfma32(a, b0, acc1[mf][0]);
        acc1[mf][1] = mfma32(a, b1, acc1[mf][1]);
      }
    }
  };

  auto WA2 = [&]() {   // leaky(acc1) -> A2 (chunk-local cols (wn*2+fc)*32+l31)
#pragma unroll
    for (int mf = 0; mf < 2; ++mf)
#pragma unroll
      for (int fc = 0; fc < 2; ++fc)
#pragma unroll
        for (int r = 0; r < 16; ++r) {
          int row = (wm * 2 + mf) * 32 + (r & 3) + 8 * (r >> 2) + 4 * lh;
          int colb = ((wn * 2 + fc) * 32 + l31) * 2;
          float v = acc1[mf][fc][r];
          v = v >= 0.f ? v : 0.01f * v;
          *(uint16_t*)(A2 + swz512(row, colb)) = f2bf(v);
        }
  };

  auto G2 = [&](int oc) {   // acc2 += A2(2 mf) @ W2 frags {wn*2, wn*2+1}
#pragma unroll 4
    for (int ks = 0; ks < 16; ++ks) {
      short8 a[2];
#pragma unroll
      for (int mf = 0; mf < 2; ++mf)
        a[mf] = *(const short8*)(A2 + swz512((wm * 2 + mf) * 32 + l31,
                                             ks * 32 + lh * 16));
#pragma unroll
      for (int nf = 0; nf < 2; ++nf) {
        short8 b = *(const short8*)(w2p +
            ((size_t)((wn * 2 + nf) * 32 + oc * 16 + ks) * 64 + lane) * 8);
        acc2[0][nf] = mfma32(a[0], b, acc2[0][nf]);
        acc2[1][nf] = mfma32(a[1], b, acc2[1][nf]);
      }
    }
  };

  // ---- schedule: 2 hidden chunks of 256, A2 single-buffered ----
  G1(0);
  WA2();
  __syncthreads();

  { // fused: G2(chunk0) || G1(chunk1) — one barrier region, interleaved
#pragma unroll
    for (int a = 0; a < 2; ++a)
#pragma unroll
      for (int b = 0; b < 2; ++b) acc1[a][b] = (f32x16)(0.f);
    const uint16_t* wb0 = w1p + (size_t)(8 + wn * 2) * (16 * 64 * 8);
    const uint16_t* wb1 = wb0 + 16 * 64 * 8;
#pragma unroll 2
    for (int ks = 0; ks < 16; ++ks) {
      // G2 step (chunk 0)
      short8 a20 = *(const short8*)(A2 + swz512((wm * 2) * 32 + l31, ks * 32 + lh * 16));
      short8 a21 = *(const short8*)(A2 + swz512((wm * 2 + 1) * 32 + l31, ks * 32 + lh * 16));
#pragma unroll
      for (int nf = 0; nf < 2; ++nf) {
        short8 b = *(const short8*)(w2p +
            ((size_t)((wn * 2 + nf) * 32 + ks) * 64 + lane) * 8);
        acc2[0][nf] = mfma32(a20, b, acc2[0][nf]);
        acc2[1][nf] = mfma32(a21, b, acc2[1][nf]);
      }
      // G1 step (chunk 1)
      short8 b0 = *(const short8*)(wb0 + ((size_t)ks * 64 + lane) * 8);
      short8 b1 = *(const short8*)(wb1 + ((size_t)ks * 64 + lane) * 8);
#pragma unroll
      for (int mf = 0; mf < 2; ++mf) {
        short8 a = *(const short8*)(Xs + swz512((wm * 2 + mf) * 32 + l31,
                                                ks * 32 + lh * 16));
        acc1[mf][0] = mfma32(a, b0, acc1[mf][0]);
        acc1[mf][1] = mfma32(a, b1, acc1[mf][1]);
      }
    }
  }
  __syncthreads();   // G2(0) done reading A2
  WA2();             // chunk-1 activations
  __syncthreads();
  G2(1);
  __syncthreads();   // A2 reads done; Xs dead (last read pre-previous bar)

  // ---- epilogue: acc2 -> bf16 into Xs (plain layout) -> coalesced stores
#pragma unroll
  for (int mf = 0; mf < 2; ++mf)
#pragma unroll
    for (int nf = 0; nf < 2; ++nf)
#pragma unroll
      for (int r = 0; r < 16; ++r) {
        int row = (wm * 2 + mf) * 32 + (r & 3) + 8 * (r >> 2) + 4 * lh;
        int col = (wn * 2 + nf) * 32 + l31;
        *(uint16_t*)(Xs + row * 512 + col * 2) = f2bf(acc2[mf][nf][r]);
      }
  __syncthreads();

  char* gdst = (char*)(g + (size_t)l * MPAD * ROUT + (size_t)tile * MTILE * ROUT);
#pragma unroll
  for (int it = 0; it < 8; ++it) {
    int off = it * 8192 + tid * 16;
    short8 v = *(const short8*)(Xs + off);
    __builtin_nontemporal_store(v, (short8*)(gdst + off));
  }
}

// ---------------------------------------------------------------------------
// K3: output rotation + fp32 store, fully coalesced (48 B per thread).
// out[n,o,l,m] = sum_c rot[n,l,m,c] * G[l][2n+c][o]
// ---------------------------------------------------------------------------
__global__ void post_out(const uint16_t* __restrict__ g, const float* __restrict__ rot,
                         float* __restrict__ out) {
  int n = blockIdx.x;
  int o = threadIdx.x;
  const float* rp = rot + (size_t)n * 24;
  float res[12];
#pragma unroll
  for (int l = 0; l < LMAX; ++l) {
    size_t base = (size_t)l * MPAD * ROUT + (size_t)(2 * n) * ROUT + o;
    float g0 = bf2f(g[base]);
    float g1 = bf2f(g[base + ROUT]);
    res[2 * l]     = rp[4 * l + 0] * g0 + rp[4 * l + 1] * g1;   // m=0
    res[2 * l + 1] = rp[4 * l + 2] * g0 + rp[4 * l + 3] * g1;   // m=1
  }
  float4* op = (float4*)(out + (size_t)(n * 256 + o) * 12);
  op[0] = make_float4(res[0], res[1], res[2], res[3]);
  op[1] = make_float4(res[4], res[5], res[6], res[7]);
  op[2] = make_float4(res[8], res[9], res[10], res[11]);
}

// ---------------------------------------------------------------------------
extern "C" void kernel_launch(void* const* d_in, const int* in_sizes, int n_in,
                              void* d_out, int out_size, void* d_ws, size_t ws_size,
                              hipStream_t stream) {
  (void)in_sizes; (void)n_in; (void)out_size;
  const float* x   = (const float*)d_in[0];
  const float* rot = (const float*)d_in[1];
  const float* W1  = (const float*)d_in[2];
  const float* W2  = (const float*)d_in[3];
  float* out = (float*)d_out;

  // Scratch plan:
  //   d_out tail (overwritten only by final post_out): W1/W2 bf16 fragments
  //   d_ws: G: 6 planes of [MPAD][ROUT] bf16 = 123,076,608 B
  const size_t w_elems = (size_t)LMAX * RHID * RIN;         // 786,432 (same W2)
  if (ws_size < (size_t)LMAX * MPAD * ROUT * 2) return;

  uint16_t* w1f = (uint16_t*)d_out + 62000000;   // well past 123MB G-free zone
  uint16_t* w2f = w1f + w_elems;
  uint16_t* g   = (uint16_t*)d_ws;

  prep_weights<<<3072, 256, 0, stream>>>(W1, W2, w1f, w2f);
  dim3 gg(LMAX, NTILES);   // l fastest: 6 siblings of a tile dispatch-adjacent
  so2_gemm<<<gg, 512, 0, stream>>>(x, rot, w1f, w2f, g);
  post_out<<<20000, 256, 0, stream>>>(g, rot, out);
}

// Round 7
// 362.621 us; speedup vs baseline: 1.2715x; 1.2715x over previous
//
#include <hip/hip_runtime.h>
#include <stdint.h>

// SO2MLP: out = so2_linear(rot_act(so2_linear(x,W1)), W2)
// Restructured: Xr = rotate(x); A = leaky(Xr@W1^T); G = A@W2^T; out = rotate_back(G).
//
// R7 = R5 pipeline (separate coalesced prep_x — R6 lesson: strided per-degree
// reads of x cause 6x HBM over-fetch) + R6's gemm core (MTILE=128, 8 waves =
// 2(wm) x 4(wn), 2x2 frags/wave => dup-free W1 AND W2 from L2, LDS traffic
// halved vs R5). LDS 128KB, 1 block/CU. Epilogue via LDS (R3 lesson: no
// sub-line global scatter).

#define LMAX 6
#define NN 20000
#define RIN 256
#define RHID 512
#define ROUT 256
#define MTILE 128            // 64 nodes x 2 components
#define NTILES 313           // 313*128 = 40064 rows
#define MPAD (NTILES*MTILE)

typedef __attribute__((ext_vector_type(8))) short short8;
typedef __attribute__((ext_vector_type(16))) float f32x16;

__device__ __forceinline__ uint16_t f2bf(float f) {
  uint32_t x = __builtin_bit_cast(uint32_t, f);
  x += 0x7fffu + ((x >> 16) & 1u);   // round-to-nearest-even
  return (uint16_t)(x >> 16);
}
__device__ __forceinline__ float bf2f(uint16_t u) {
  return __builtin_bit_cast(float, ((uint32_t)u) << 16);
}

__device__ __forceinline__ f32x16 mfma32(short8 a, short8 b, f32x16 c) {
  return __builtin_amdgcn_mfma_f32_32x32x16_bf16(a, b, c, 0, 0, 0);
}

// 512B-row LDS address with 16B-granule swizzle (verified R4-R6: 0 conflicts)
__device__ __forceinline__ int swz512(int row, int colb) {
  return row * 512 + ((((colb >> 4) ^ row) & 31) << 4) + (colb & 15);
}

// ---------------------------------------------------------------------------
// K1a: weights fp32 -> bf16, 32x32x16 B-fragment-linear (verified R4-R6).
// B frag: col = lane&31, k = (lane>>5)*8 + e; (frag,kstep) = 1KB contiguous.
// ---------------------------------------------------------------------------
__global__ void prep_weights(const float* __restrict__ W1, const float* __restrict__ W2,
                             uint16_t* __restrict__ w1f, uint16_t* __restrict__ w2f) {
  int idx = blockIdx.x * 256 + threadIdx.x;
  if (idx >= LMAX * RHID * RIN) return;
  {
    // W1[l][o][i], K=256 -> 16 ksteps; 16 out-frags of 32
    int l = idx / (RHID * RIN);
    int rem = idx - l * (RHID * RIN);
    int o = rem >> 8;
    int i = rem & 255;
    int lane = ((i >> 3) & 1) * 32 + (o & 31);
    size_t dst = (size_t)l * (RHID * RIN) +
                 ((((size_t)(o >> 5) * 16 + (i >> 4)) * 64 + lane) * 8 + (i & 7));
    w1f[dst] = f2bf(W1[idx]);
  }
  {
    // W2[l][o][j], K=512 -> 32 ksteps; 8 out-frags of 32
    int l = idx / (ROUT * RHID);
    int rem = idx - l * (ROUT * RHID);
    int o = rem >> 9;
    int j = rem & 511;
    int lane = ((j >> 3) & 1) * 32 + (o & 31);
    size_t dst = (size_t)l * (ROUT * RHID) +
                 ((((size_t)(o >> 5) * 32 + (j >> 4)) * 64 + lane) * 8 + (j & 7));
    w2f[dst] = f2bf(W2[idx]);
  }
}

// ---------------------------------------------------------------------------
// K1b: input rotation + bf16 cast + degree-planar relayout (coalesced both
// sides; the ONLY kernel allowed to read x — R6 lesson).
// Xr[l][m=2n+c][i] = sum_m' x[n,i,l,m'] * rot[n,l,m',c]
// ---------------------------------------------------------------------------
__global__ void prep_x(const float* __restrict__ x, const float* __restrict__ rot,
                       uint16_t* __restrict__ xr) {
  int t = blockIdx.x * 256 + threadIdx.x;   // t = n*256 + i
  if (t >= NN * RIN) return;
  int n = t >> 8, i = t & 255;
  const float4* xp = (const float4*)(x + (size_t)t * 12);
  float4 v0 = xp[0], v1 = xp[1], v2 = xp[2];
  float xv[12] = {v0.x, v0.y, v0.z, v0.w, v1.x, v1.y, v1.z, v1.w, v2.x, v2.y, v2.z, v2.w};
  const float* rp = rot + (size_t)n * 24;   // rot[n][l][m][c]
#pragma unroll
  for (int l = 0; l < LMAX; ++l) {
    float c0 = xv[2 * l], c1 = xv[2 * l + 1];
    float r00 = rp[4 * l + 0], r01 = rp[4 * l + 1];
    float r10 = rp[4 * l + 2], r11 = rp[4 * l + 3];
    float a0 = c0 * r00 + c1 * r10;   // c=0
    float a1 = c0 * r01 + c1 * r11;   // c=1
    size_t base = (size_t)l * MPAD * RIN + (size_t)(2 * n) * RIN + i;
    xr[base] = f2bf(a0);
    xr[base + RIN] = f2bf(a1);
  }
}

// ---------------------------------------------------------------------------
// K2: dual GEMM per (degree, 128-row tile), 32x32x16 MFMA.
// 512 thr = 8 waves = 2(wm) x 4(wn). Per wave: 2 m-frags x 2 n-frags in both
// GEMMs => W1 and W2 each read exactly once per block (dup-free).
// A-frag: row=lane&31, k=(lane>>5)*8+e; C/D: col=lane&31,
// row=(r&3)+8*(r>>2)+4*(lane>>5)  (all verified R4-R6).
// ---------------------------------------------------------------------------
__global__ __launch_bounds__(512, 2) void so2_gemm(
    const uint16_t* __restrict__ xr,
    const uint16_t* __restrict__ w1f,
    const uint16_t* __restrict__ w2f,
    uint16_t* __restrict__ g) {
  __shared__ alignas(16) uint8_t Xs[MTILE * 512];   // 64KB, swizzled
  __shared__ alignas(16) uint8_t A2[MTILE * 512];   // 64KB, swizzled

  const int tile = blockIdx.x;         // same-l blocks adjacent => W hot in L2
  const int l = blockIdx.y;
  const int m0 = tile * MTILE;
  const int tid = threadIdx.x;
  const int lane = tid & 63;
  const int wid = tid >> 6;
  const int l31 = lane & 31;
  const int lh = lane >> 5;
  const int wm = wid & 1;              // M half (2 m-frags each)
  const int wn = wid >> 1;             // N quarter (2 n-frags each)

  const uint16_t* w1p = w1f + (size_t)l * (RHID * RIN);
  const uint16_t* w2p = w2f + (size_t)l * (ROUT * RHID);

  // ---- stage Xr tile (128 rows x 512B) into swizzled LDS ----
  const char* xsrc = (const char*)(xr + (size_t)l * MPAD * RIN + (size_t)m0 * RIN);
#pragma unroll
  for (int it = 0; it < 8; ++it) {
    int off = it * 8192 + tid * 16;
    int row = off >> 9;
    int colb = off & 511;
    short8 v = __builtin_nontemporal_load((const short8*)(xsrc + off));
    *(short8*)(Xs + swz512(row, colb)) = v;
  }
  __syncthreads();

  f32x16 acc1[2][2];   // [mf][fc] G1 chunk accum
  f32x16 acc2[2][2];   // [mf][nf] G2 running accum
#pragma unroll
  for (int a = 0; a < 2; ++a)
#pragma unroll
    for (int b = 0; b < 2; ++b) acc2[a][b] = (f32x16)(0.f);

  auto G1 = [&](int oc) {   // acc1 = Xs(2 mf) @ W1 frags {oc*8+wn*2, +1}
#pragma unroll
    for (int a = 0; a < 2; ++a)
#pragma unroll
      for (int b = 0; b < 2; ++b) acc1[a][b] = (f32x16)(0.f);
    const uint16_t* wb0 = w1p + (size_t)(oc * 8 + wn * 2) * (16 * 64 * 8);
    const uint16_t* wb1 = wb0 + 16 * 64 * 8;
#pragma unroll 4
    for (int ks = 0; ks < 16; ++ks) {
      short8 b0 = *(const short8*)(wb0 + ((size_t)ks * 64 + lane) * 8);
      short8 b1 = *(const short8*)(wb1 + ((size_t)ks * 64 + lane) * 8);
#pragma unroll
      for (int mf = 0; mf < 2; ++mf) {
        short8 a = *(const short8*)(Xs + swz512((wm * 2 + mf) * 32 + l31,
                                                ks * 32 + lh * 16));
        acc1[mf][0] = mfma32(a, b0, acc1[mf][0]);
        acc1[mf][1] = mfma32(a, b1, acc1[mf][1]);
      }
    }
  };

  auto WA2 = [&]() {   // leaky(acc1) -> A2 (chunk-local cols (wn*2+fc)*32+l31)
#pragma unroll
    for (int mf = 0; mf < 2; ++mf)
#pragma unroll
      for (int fc = 0; fc < 2; ++fc)
#pragma unroll
        for (int r = 0; r < 16; ++r) {
          int row = (wm * 2 + mf) * 32 + (r & 3) + 8 * (r >> 2) + 4 * lh;
          int colb = ((wn * 2 + fc) * 32 + l31) * 2;
          float v = acc1[mf][fc][r];
          v = v >= 0.f ? v : 0.01f * v;
          *(uint16_t*)(A2 + swz512(row, colb)) = f2bf(v);
        }
  };

  auto G2 = [&](int oc) {   // acc2 += A2(2 mf) @ W2 frags {wn*2, wn*2+1}
#pragma unroll 4
    for (int ks = 0; ks < 16; ++ks) {
      short8 a[2];
#pragma unroll
      for (int mf = 0; mf < 2; ++mf)
        a[mf] = *(const short8*)(A2 + swz512((wm * 2 + mf) * 32 + l31,
                                             ks * 32 + lh * 16));
#pragma unroll
      for (int nf = 0; nf < 2; ++nf) {
        short8 b = *(const short8*)(w2p +
            ((size_t)((wn * 2 + nf) * 32 + oc * 16 + ks) * 64 + lane) * 8);
        acc2[0][nf] = mfma32(a[0], b, acc2[0][nf]);
        acc2[1][nf] = mfma32(a[1], b, acc2[1][nf]);
      }
    }
  };

  // ---- schedule: 2 hidden chunks of 256, A2 single-buffered ----
  G1(0);
  WA2();
  __syncthreads();

  { // fused: G2(chunk0) || G1(chunk1) — one barrier region, interleaved
#pragma unroll
    for (int a = 0; a < 2; ++a)
#pragma unroll
      for (int b = 0; b < 2; ++b) acc1[a][b] = (f32x16)(0.f);
    const uint16_t* wb0 = w1p + (size_t)(8 + wn * 2) * (16 * 64 * 8);
    const uint16_t* wb1 = wb0 + 16 * 64 * 8;
#pragma unroll 2
    for (int ks = 0; ks < 16; ++ks) {
      // G2 step (chunk 0)
      short8 a20 = *(const short8*)(A2 + swz512((wm * 2) * 32 + l31, ks * 32 + lh * 16));
      short8 a21 = *(const short8*)(A2 + swz512((wm * 2 + 1) * 32 + l31, ks * 32 + lh * 16));
#pragma unroll
      for (int nf = 0; nf < 2; ++nf) {
        short8 b = *(const short8*)(w2p +
            ((size_t)((wn * 2 + nf) * 32 + ks) * 64 + lane) * 8);
        acc2[0][nf] = mfma32(a20, b, acc2[0][nf]);
        acc2[1][nf] = mfma32(a21, b, acc2[1][nf]);
      }
      // G1 step (chunk 1)
      short8 b0 = *(const short8*)(wb0 + ((size_t)ks * 64 + lane) * 8);
      short8 b1 = *(const short8*)(wb1 + ((size_t)ks * 64 + lane) * 8);
#pragma unroll
      for (int mf = 0; mf < 2; ++mf) {
        short8 a = *(const short8*)(Xs + swz512((wm * 2 + mf) * 32 + l31,
                                                ks * 32 + lh * 16));
        acc1[mf][0] = mfma32(a, b0, acc1[mf][0]);
        acc1[mf][1] = mfma32(a, b1, acc1[mf][1]);
      }
    }
  }
  __syncthreads();   // G2(0) done reading A2
  WA2();             // chunk-1 activations
  __syncthreads();
  G2(1);
  __syncthreads();   // A2 reads done; Xs dead

  // ---- epilogue: acc2 -> bf16 into Xs (plain layout) -> coalesced stores
#pragma unroll
  for (int mf = 0; mf < 2; ++mf)
#pragma unroll
    for (int nf = 0; nf < 2; ++nf)
#pragma unroll
      for (int r = 0; r < 16; ++r) {
        int row = (wm * 2 + mf) * 32 + (r & 3) + 8 * (r >> 2) + 4 * lh;
        int col = (wn * 2 + nf) * 32 + l31;
        *(uint16_t*)(Xs + row * 512 + col * 2) = f2bf(acc2[mf][nf][r]);
      }
  __syncthreads();

  char* gdst = (char*)(g + (size_t)l * MPAD * ROUT + (size_t)m0 * ROUT);
#pragma unroll
  for (int it = 0; it < 8; ++it) {
    int off = it * 8192 + tid * 16;
    short8 v = *(const short8*)(Xs + off);
    __builtin_nontemporal_store(v, (short8*)(gdst + off));
  }
}

// ---------------------------------------------------------------------------
// K3: output rotation + fp32 store, fully coalesced (48 B per thread).
// out[n,o,l,m] = sum_c rot[n,l,m,c] * G[l][2n+c][o]
// ---------------------------------------------------------------------------
__global__ void post_out(const uint16_t* __restrict__ g, const float* __restrict__ rot,
                         float* __restrict__ out) {
  int n = blockIdx.x;
  int o = threadIdx.x;
  const float* rp = rot + (size_t)n * 24;
  float res[12];
#pragma unroll
  for (int l = 0; l < LMAX; ++l) {
    size_t base = (size_t)l * MPAD * ROUT + (size_t)(2 * n) * ROUT + o;
    float g0 = bf2f(g[base]);
    float g1 = bf2f(g[base + ROUT]);
    res[2 * l]     = rp[4 * l + 0] * g0 + rp[4 * l + 1] * g1;   // m=0
    res[2 * l + 1] = rp[4 * l + 2] * g0 + rp[4 * l + 3] * g1;   // m=1
  }
  float4* op = (float4*)(out + (size_t)(n * 256 + o) * 12);
  op[0] = make_float4(res[0], res[1], res[2], res[3]);
  op[1] = make_float4(res[4], res[5], res[6], res[7]);
  op[2] = make_float4(res[8], res[9], res[10], res[11]);
}

// ---------------------------------------------------------------------------
extern "C" void kernel_launch(void* const* d_in, const int* in_sizes, int n_in,
                              void* d_out, int out_size, void* d_ws, size_t ws_size,
                              hipStream_t stream) {
  (void)in_sizes; (void)n_in; (void)out_size;
  const float* x   = (const float*)d_in[0];
  const float* rot = (const float*)d_in[1];
  const float* W1  = (const float*)d_in[2];
  const float* W2  = (const float*)d_in[3];
  float* out = (float*)d_out;

  // Scratch plan:
  //   d_out (245.76 MB, overwritten by K3 at the end) doubles as scratch:
  //     [0, 123.08 MB)          Xr: 6 planes of [MPAD][RIN] bf16
  //     [123.08, 124.65 MB)     W1 bf16 fragment-linear
  //     [124.65, 126.22 MB)     W2 bf16 fragment-linear
  //   d_ws: G: 6 planes of [MPAD][ROUT] bf16 = 123,076,608 B
  const size_t xr_elems = (size_t)LMAX * MPAD * RIN;        // 61,538,304
  const size_t w_elems  = (size_t)LMAX * RHID * RIN;        // 786,432 (same W2)
  if (ws_size < (size_t)LMAX * MPAD * ROUT * 2) return;     // need 123,076,608 B

  uint16_t* xr  = (uint16_t*)d_out;
  uint16_t* w1f = xr + xr_elems;
  uint16_t* w2f = w1f + w_elems;
  uint16_t* g   = (uint16_t*)d_ws;

  prep_weights<<<3072, 256, 0, stream>>>(W1, W2, w1f, w2f);
  prep_x<<<20000, 256, 0, stream>>>(x, rot, xr);
  dim3 gg(NTILES, LMAX);   // same-l blocks adjacent: W stays hot in each L2
  so2_gemm<<<gg, 512, 0, stream>>>(xr, w1f, w2f, g);
  post_out<<<20000, 256, 0, stream>>>(g, rot, out);
}

// Round 8
// 359.989 us; speedup vs baseline: 1.2808x; 1.0073x over previous
//
#include <hip/hip_runtime.h>
#include <stdint.h>

// SO2MLP: out = so2_linear(rot_act(so2_linear(x,W1)), W2)
// Restructured: Xr = rotate(x); A = leaky(Xr@W1^T); G = A@W2^T; out = rotate_back(G).
//
// R8 = R7 + swapped MFMA operands in BOTH gemms (D = [o][m] instead of [m][o]).
// 32x32 A-frag and B-frag have IDENTICAL per-lane addressing (row/col=lane&31,
// k-octet=lane>>5), so all loads are unchanged; but each lane's D now holds
// 4 quads of 4 CONSECUTIVE hidden/out columns at a fixed m-row ->
// WA2/epilogue become packed 8B ds_write_b64 (16/lane) instead of 64 scalar
// b16 -> kills ~9k LDS-pipe cycles/block that sat in barrier phases.
// Everything else (prep_x, swizzle, schedule, epilogue-via-LDS) = R7.

#define LMAX 6
#define NN 20000
#define RIN 256
#define RHID 512
#define ROUT 256
#define MTILE 128            // 64 nodes x 2 components
#define NTILES 313           // 313*128 = 40064 rows
#define MPAD (NTILES*MTILE)

typedef __attribute__((ext_vector_type(8))) short short8;
typedef __attribute__((ext_vector_type(16))) float f32x16;

__device__ __forceinline__ uint16_t f2bf(float f) {
  uint32_t x = __builtin_bit_cast(uint32_t, f);
  x += 0x7fffu + ((x >> 16) & 1u);   // round-to-nearest-even
  return (uint16_t)(x >> 16);
}
__device__ __forceinline__ float bf2f(uint16_t u) {
  return __builtin_bit_cast(float, ((uint32_t)u) << 16);
}
__device__ __forceinline__ float lrelu(float v) {
  return v >= 0.f ? v : 0.01f * v;
}
__device__ __forceinline__ uint32_t pk2(float a, float b) {
  return (uint32_t)f2bf(a) | ((uint32_t)f2bf(b) << 16);
}

__device__ __forceinline__ f32x16 mfma32(short8 a, short8 b, f32x16 c) {
  return __builtin_amdgcn_mfma_f32_32x32x16_bf16(a, b, c, 0, 0, 0);
}

// 512B-row LDS address with 16B-granule swizzle (verified R4-R7: 0 conflicts)
__device__ __forceinline__ int swz512(int row, int colb) {
  return row * 512 + ((((colb >> 4) ^ row) & 31) << 4) + (colb & 15);
}

// ---------------------------------------------------------------------------
// K1a: weights fp32 -> bf16, 32x32x16 fragment-linear (verified R4-R7).
// Frag: row-or-col = lane&31, k = (lane>>5)*8 + e; (frag,kstep) = 1KB.
// Same layout serves as A-frag (rows) or B-frag (cols).
// ---------------------------------------------------------------------------
__global__ void prep_weights(const float* __restrict__ W1, const float* __restrict__ W2,
                             uint16_t* __restrict__ w1f, uint16_t* __restrict__ w2f) {
  int idx = blockIdx.x * 256 + threadIdx.x;
  if (idx >= LMAX * RHID * RIN) return;
  {
    // W1[l][o][i], K=256 -> 16 ksteps; 16 o-frags of 32
    int l = idx / (RHID * RIN);
    int rem = idx - l * (RHID * RIN);
    int o = rem >> 8;
    int i = rem & 255;
    int lane = ((i >> 3) & 1) * 32 + (o & 31);
    size_t dst = (size_t)l * (RHID * RIN) +
                 ((((size_t)(o >> 5) * 16 + (i >> 4)) * 64 + lane) * 8 + (i & 7));
    w1f[dst] = f2bf(W1[idx]);
  }
  {
    // W2[l][o][j], K=512 -> 32 ksteps; 8 o-frags of 32
    int l = idx / (ROUT * RHID);
    int rem = idx - l * (ROUT * RHID);
    int o = rem >> 9;
    int j = rem & 511;
    int lane = ((j >> 3) & 1) * 32 + (o & 31);
    size_t dst = (size_t)l * (ROUT * RHID) +
                 ((((size_t)(o >> 5) * 32 + (j >> 4)) * 64 + lane) * 8 + (j & 7));
    w2f[dst] = f2bf(W2[idx]);
  }
}

// ---------------------------------------------------------------------------
// K1b: input rotation + bf16 cast + degree-planar relayout (coalesced both
// sides; the ONLY kernel allowed to read x — R6 lesson).
// ---------------------------------------------------------------------------
__global__ void prep_x(const float* __restrict__ x, const float* __restrict__ rot,
                       uint16_t* __restrict__ xr) {
  int t = blockIdx.x * 256 + threadIdx.x;   // t = n*256 + i
  if (t >= NN * RIN) return;
  int n = t >> 8, i = t & 255;
  const float4* xp = (const float4*)(x + (size_t)t * 12);
  float4 v0 = xp[0], v1 = xp[1], v2 = xp[2];
  float xv[12] = {v0.x, v0.y, v0.z, v0.w, v1.x, v1.y, v1.z, v1.w, v2.x, v2.y, v2.z, v2.w};
  const float* rp = rot + (size_t)n * 24;   // rot[n][l][m][c]
#pragma unroll
  for (int l = 0; l < LMAX; ++l) {
    float c0 = xv[2 * l], c1 = xv[2 * l + 1];
    float r00 = rp[4 * l + 0], r01 = rp[4 * l + 1];
    float r10 = rp[4 * l + 2], r11 = rp[4 * l + 3];
    float a0 = c0 * r00 + c1 * r10;   // c=0
    float a1 = c0 * r01 + c1 * r11;   // c=1
    size_t base = (size_t)l * MPAD * RIN + (size_t)(2 * n) * RIN + i;
    xr[base] = f2bf(a0);
    xr[base + RIN] = f2bf(a1);
  }
}

// ---------------------------------------------------------------------------
// K2: dual GEMM per (degree, 128-row tile), 32x32x16 MFMA, SWAPPED operands.
// 512 thr = 8 waves = 2(wm: m-block pair) x 4(wn: o-frag pair).
// G1: mfma(A=W1frag, B=Xsfrag) -> D[o][m]; G2: mfma(A=W2frag, B=A2frag).
// Frag addressing identical to R7 (verified); D: col(=m)=lane&31,
// row(=o) = (r&3)+8*(r>>2)+4*(lane>>5)  -> per-lane quads of consecutive o.
// ---------------------------------------------------------------------------
__global__ __launch_bounds__(512, 2) void so2_gemm(
    const uint16_t* __restrict__ xr,
    const uint16_t* __restrict__ w1f,
    const uint16_t* __restrict__ w2f,
    uint16_t* __restrict__ g) {
  __shared__ alignas(16) uint8_t Xs[MTILE * 512];   // 64KB, swizzled
  __shared__ alignas(16) uint8_t A2[MTILE * 512];   // 64KB, swizzled

  const int tile = blockIdx.x;         // same-l blocks adjacent => W hot in L2
  const int l = blockIdx.y;
  const int m0 = tile * MTILE;
  const int tid = threadIdx.x;
  const int lane = tid & 63;
  const int wid = tid >> 6;
  const int l31 = lane & 31;
  const int lh = lane >> 5;
  const int wm = wid & 1;              // m-block pair {wm*2, wm*2+1}
  const int wn = wid >> 1;             // o-frag pair {wn*2, wn*2+1}

  const uint16_t* w1p = w1f + (size_t)l * (RHID * RIN);
  const uint16_t* w2p = w2f + (size_t)l * (ROUT * RHID);

  // ---- stage Xr tile (128 rows x 512B) into swizzled LDS ----
  const char* xsrc = (const char*)(xr + (size_t)l * MPAD * RIN + (size_t)m0 * RIN);
#pragma unroll
  for (int it = 0; it < 8; ++it) {
    int off = it * 8192 + tid * 16;
    int row = off >> 9;
    int colb = off & 511;
    short8 v = __builtin_nontemporal_load((const short8*)(xsrc + off));
    *(short8*)(Xs + swz512(row, colb)) = v;
  }
  __syncthreads();

  f32x16 acc1[2][2];   // [fi][mbi] G1 chunk accum: o-frag wn*2+fi, m-block wm*2+mbi
  f32x16 acc2[2][2];   // [foi][mbi] G2 running accum
#pragma unroll
  for (int a = 0; a < 2; ++a)
#pragma unroll
    for (int b = 0; b < 2; ++b) acc2[a][b] = (f32x16)(0.f);

  auto G1 = [&](int oc) {
#pragma unroll
    for (int a = 0; a < 2; ++a)
#pragma unroll
      for (int b = 0; b < 2; ++b) acc1[a][b] = (f32x16)(0.f);
    const uint16_t* wb0 = w1p + (size_t)(oc * 8 + wn * 2) * (16 * 64 * 8);
    const uint16_t* wb1 = wb0 + 16 * 64 * 8;
#pragma unroll 4
    for (int ks = 0; ks < 16; ++ks) {
      short8 a0 = *(const short8*)(wb0 + ((size_t)ks * 64 + lane) * 8);
      short8 a1 = *(const short8*)(wb1 + ((size_t)ks * 64 + lane) * 8);
#pragma unroll
      for (int mbi = 0; mbi < 2; ++mbi) {
        short8 b = *(const short8*)(Xs + swz512((wm * 2 + mbi) * 32 + l31,
                                                ks * 32 + lh * 16));
        acc1[0][mbi] = mfma32(a0, b, acc1[0][mbi]);
        acc1[1][mbi] = mfma32(a1, b, acc1[1][mbi]);
      }
    }
  };

  auto WA2 = [&]() {   // leaky(acc1) -> A2[m-row][hidden-chunk col], packed b64
#pragma unroll
    for (int fi = 0; fi < 2; ++fi)
#pragma unroll
      for (int mbi = 0; mbi < 2; ++mbi) {
        int mrow = (wm * 2 + mbi) * 32 + l31;
#pragma unroll
        for (int q = 0; q < 4; ++q) {
          // lane's quad q = hidden cols {base..base+3}, base = frag*32+8q+4lh
          uint2 pv;
          pv.x = pk2(lrelu(acc1[fi][mbi][4 * q + 0]), lrelu(acc1[fi][mbi][4 * q + 1]));
          pv.y = pk2(lrelu(acc1[fi][mbi][4 * q + 2]), lrelu(acc1[fi][mbi][4 * q + 3]));
          int colb = (wn * 2 + fi) * 64 + q * 16 + lh * 8;
          *(uint2*)(A2 + swz512(mrow, colb)) = pv;
        }
      }
  };

  auto G2 = [&](int oc) {   // acc2 += W2frags(wn*2..+1) x A2(m-blocks wm*2..+1)
#pragma unroll 4
    for (int ks = 0; ks < 16; ++ks) {
      short8 b0 = *(const short8*)(A2 + swz512((wm * 2) * 32 + l31, ks * 32 + lh * 16));
      short8 b1 = *(const short8*)(A2 + swz512((wm * 2 + 1) * 32 + l31, ks * 32 + lh * 16));
#pragma unroll
      for (int foi = 0; foi < 2; ++foi) {
        short8 a = *(const short8*)(w2p +
            ((size_t)((wn * 2 + foi) * 32 + oc * 16 + ks) * 64 + lane) * 8);
        acc2[foi][0] = mfma32(a, b0, acc2[foi][0]);
        acc2[foi][1] = mfma32(a, b1, acc2[foi][1]);
      }
    }
  };

  // ---- schedule: 2 hidden chunks of 256, A2 single-buffered ----
  G1(0);
  WA2();
  __syncthreads();

  { // fused: G2(chunk0) || G1(chunk1) — one barrier region, interleaved
#pragma unroll
    for (int a = 0; a < 2; ++a)
#pragma unroll
      for (int b = 0; b < 2; ++b) acc1[a][b] = (f32x16)(0.f);
    const uint16_t* wb0 = w1p + (size_t)(8 + wn * 2) * (16 * 64 * 8);
    const uint16_t* wb1 = wb0 + 16 * 64 * 8;
#pragma unroll 2
    for (int ks = 0; ks < 16; ++ks) {
      // G2 step (chunk 0)
      short8 b20 = *(const short8*)(A2 + swz512((wm * 2) * 32 + l31, ks * 32 + lh * 16));
      short8 b21 = *(const short8*)(A2 + swz512((wm * 2 + 1) * 32 + l31, ks * 32 + lh * 16));
#pragma unroll
      for (int foi = 0; foi < 2; ++foi) {
        short8 a = *(const short8*)(w2p +
            ((size_t)((wn * 2 + foi) * 32 + ks) * 64 + lane) * 8);
        acc2[foi][0] = mfma32(a, b20, acc2[foi][0]);
        acc2[foi][1] = mfma32(a, b21, acc2[foi][1]);
      }
      // G1 step (chunk 1)
      short8 a10 = *(const short8*)(wb0 + ((size_t)ks * 64 + lane) * 8);
      short8 a11 = *(const short8*)(wb1 + ((size_t)ks * 64 + lane) * 8);
#pragma unroll
      for (int mbi = 0; mbi < 2; ++mbi) {
        short8 b = *(const short8*)(Xs + swz512((wm * 2 + mbi) * 32 + l31,
                                                ks * 32 + lh * 16));
        acc1[0][mbi] = mfma32(a10, b, acc1[0][mbi]);
        acc1[1][mbi] = mfma32(a11, b, acc1[1][mbi]);
      }
    }
  }
  __syncthreads();   // G2(0) done reading A2
  WA2();             // chunk-1 activations
  __syncthreads();
  G2(1);
  __syncthreads();   // A2 reads done; Xs dead

  // ---- epilogue: acc2 -> bf16 packed b64 into Xs (swizzled) -> 16B stores
#pragma unroll
  for (int foi = 0; foi < 2; ++foi)
#pragma unroll
    for (int mbi = 0; mbi < 2; ++mbi) {
      int mrow = (wm * 2 + mbi) * 32 + l31;
#pragma unroll
      for (int q = 0; q < 4; ++q) {
        uint2 pv;
        pv.x = pk2(acc2[foi][mbi][4 * q + 0], acc2[foi][mbi][4 * q + 1]);
        pv.y = pk2(acc2[foi][mbi][4 * q + 2], acc2[foi][mbi][4 * q + 3]);
        int colb = (wn * 2 + foi) * 64 + q * 16 + lh * 8;
        *(uint2*)(Xs + swz512(mrow, colb)) = pv;
      }
    }
  __syncthreads();

  char* gdst = (char*)(g + (size_t)l * MPAD * ROUT + (size_t)m0 * ROUT);
#pragma unroll
  for (int it = 0; it < 8; ++it) {
    int off = it * 8192 + tid * 16;
    int row = off >> 9;
    int colb = off & 511;
    short8 v = *(const short8*)(Xs + swz512(row, colb));
    __builtin_nontemporal_store(v, (short8*)(gdst + off));
  }
}

// ---------------------------------------------------------------------------
// K3: output rotation + fp32 store, fully coalesced (48 B per thread).
// out[n,o,l,m] = sum_c rot[n,l,m,c] * G[l][2n+c][o]
// ---------------------------------------------------------------------------
__global__ void post_out(const uint16_t* __restrict__ g, const float* __restrict__ rot,
                         float* __restrict__ out) {
  int n = blockIdx.x;
  int o = threadIdx.x;
  const float* rp = rot + (size_t)n * 24;
  float res[12];
#pragma unroll
  for (int l = 0; l < LMAX; ++l) {
    size_t base = (size_t)l * MPAD * ROUT + (size_t)(2 * n) * ROUT + o;
    float g0 = bf2f(g[base]);
    float g1 = bf2f(g[base + ROUT]);
    res[2 * l]     = rp[4 * l + 0] * g0 + rp[4 * l + 1] * g1;   // m=0
    res[2 * l + 1] = rp[4 * l + 2] * g0 + rp[4 * l + 3] * g1;   // m=1
  }
  float4* op = (float4*)(out + (size_t)(n * 256 + o) * 12);
  op[0] = make_float4(res[0], res[1], res[2], res[3]);
  op[1] = make_float4(res[4], res[5], res[6], res[7]);
  op[2] = make_float4(res[8], res[9], res[10], res[11]);
}

// ---------------------------------------------------------------------------
extern "C" void kernel_launch(void* const* d_in, const int* in_sizes, int n_in,
                              void* d_out, int out_size, void* d_ws, size_t ws_size,
                              hipStream_t stream) {
  (void)in_sizes; (void)n_in; (void)out_size;
  const float* x   = (const float*)d_in[0];
  const float* rot = (const float*)d_in[1];
  const float* W1  = (const float*)d_in[2];
  const float* W2  = (const float*)d_in[3];
  float* out = (float*)d_out;

  // Scratch plan:
  //   d_out (245.76 MB, overwritten by K3 at the end) doubles as scratch:
  //     [0, 123.08 MB)          Xr: 6 planes of [MPAD][RIN] bf16
  //     [123.08, 124.65 MB)     W1 bf16 fragment-linear
  //     [124.65, 126.22 MB)     W2 bf16 fragment-linear
  //   d_ws: G: 6 planes of [MPAD][ROUT] bf16 = 123,076,608 B
  const size_t xr_elems = (size_t)LMAX * MPAD * RIN;        // 61,538,304
  const size_t w_elems  = (size_t)LMAX * RHID * RIN;        // 786,432 (same W2)
  if (ws_size < (size_t)LMAX * MPAD * ROUT * 2) return;     // need 123,076,608 B

  uint16_t* xr  = (uint16_t*)d_out;
  uint16_t* w1f = xr + xr_elems;
  uint16_t* w2f = w1f + w_elems;
  uint16_t* g   = (uint16_t*)d_ws;

  prep_weights<<<3072, 256, 0, stream>>>(W1, W2, w1f, w2f);
  prep_x<<<20000, 256, 0, stream>>>(x, rot, xr);
  dim3 gg(NTILES, LMAX);   // same-l blocks adjacent: W stays hot in each L2
  so2_gemm<<<gg, 512, 0, stream>>>(xr, w1f, w2f, g);
  post_out<<<20000, 256, 0, stream>>>(g, rot, out);
}

// Round 9
// 337.674 us; speedup vs baseline: 1.3654x; 1.0661x over previous
//
#include <hip/hip_runtime.h>
#include <stdint.h>

// SO2MLP: out = so2_linear(rot_act(so2_linear(x,W1)), W2)
// Restructured: Xr = rotate(x); A = leaky(Xr@W1^T); G = A@W2^T; out = rotate_back(G).
//
// R9 = R8's swapped-operand dual GEMM, re-tiled for overlap:
//   MTILE 128->64, waves 8->4 (256 thr), LDS 128KB->64KB => 2 blocks/CU
//   (two independent barrier domains per CU; R5-R8 were phase-serialization
//   bound at 1 block/CU with every pipe <25% busy).
//   Per-wave rectangle stays 2x2 (frags x m-blocks) in both GEMMs => per-CU
//   LDS instruction count unchanged, W1/W2 still dup-free per block.
// + v_cvt_pk_bf16_f32 (1 inst / 2 values) replaces 3-op integer RNE in
//   WA2/epilogue (T12 recipe).

#define LMAX 6
#define NN 20000
#define RIN 256
#define RHID 512
#define ROUT 256
#define MTILE 64             // 32 nodes x 2 components
#define NTILES 626           // 626*64 = 40064 rows
#define MPAD (NTILES*MTILE)

typedef __attribute__((ext_vector_type(8))) short short8;
typedef __attribute__((ext_vector_type(16))) float f32x16;

__device__ __forceinline__ uint16_t f2bf(float f) {
  uint32_t x = __builtin_bit_cast(uint32_t, f);
  x += 0x7fffu + ((x >> 16) & 1u);   // round-to-nearest-even
  return (uint16_t)(x >> 16);
}
__device__ __forceinline__ float bf2f(uint16_t u) {
  return __builtin_bit_cast(float, ((uint32_t)u) << 16);
}
__device__ __forceinline__ float lrelu(float v) {
  return v >= 0.f ? v : 0.01f * v;
}
// packed bf16 pair: lo16 = cvt(a), hi16 = cvt(b)  (RNE on gfx950)
__device__ __forceinline__ uint32_t cvtpk(float a, float b) {
  uint32_t r;
  asm("v_cvt_pk_bf16_f32 %0, %1, %2" : "=v"(r) : "v"(a), "v"(b));
  return r;
}

__device__ __forceinline__ f32x16 mfma32(short8 a, short8 b, f32x16 c) {
  return __builtin_amdgcn_mfma_f32_32x32x16_bf16(a, b, c, 0, 0, 0);
}

// 512B-row LDS address with 16B-granule swizzle (verified R4-R8: ~0 conflicts)
__device__ __forceinline__ int swz512(int row, int colb) {
  return row * 512 + ((((colb >> 4) ^ row) & 31) << 4) + (colb & 15);
}

// ---------------------------------------------------------------------------
// K1a: weights fp32 -> bf16, 32x32x16 fragment-linear (verified R4-R8).
// Frag: row-or-col = lane&31, k = (lane>>5)*8 + e; (frag,kstep) = 1KB.
// ---------------------------------------------------------------------------
__global__ void prep_weights(const float* __restrict__ W1, const float* __restrict__ W2,
                             uint16_t* __restrict__ w1f, uint16_t* __restrict__ w2f) {
  int idx = blockIdx.x * 256 + threadIdx.x;
  if (idx >= LMAX * RHID * RIN) return;
  {
    // W1[l][o][i], K=256 -> 16 ksteps; 16 o-frags of 32
    int l = idx / (RHID * RIN);
    int rem = idx - l * (RHID * RIN);
    int o = rem >> 8;
    int i = rem & 255;
    int lane = ((i >> 3) & 1) * 32 + (o & 31);
    size_t dst = (size_t)l * (RHID * RIN) +
                 ((((size_t)(o >> 5) * 16 + (i >> 4)) * 64 + lane) * 8 + (i & 7));
    w1f[dst] = f2bf(W1[idx]);
  }
  {
    // W2[l][o][j], K=512 -> 32 ksteps; 8 o-frags of 32
    int l = idx / (ROUT * RHID);
    int rem = idx - l * (ROUT * RHID);
    int o = rem >> 9;
    int j = rem & 511;
    int lane = ((j >> 3) & 1) * 32 + (o & 31);
    size_t dst = (size_t)l * (ROUT * RHID) +
                 ((((size_t)(o >> 5) * 32 + (j >> 4)) * 64 + lane) * 8 + (j & 7));
    w2f[dst] = f2bf(W2[idx]);
  }
}

// ---------------------------------------------------------------------------
// K1b: input rotation + bf16 cast + degree-planar relayout (coalesced both
// sides; the ONLY kernel allowed to read x — R6 lesson).
// ---------------------------------------------------------------------------
__global__ void prep_x(const float* __restrict__ x, const float* __restrict__ rot,
                       uint16_t* __restrict__ xr) {
  int t = blockIdx.x * 256 + threadIdx.x;   // t = n*256 + i
  if (t >= NN * RIN) return;
  int n = t >> 8, i = t & 255;
  const float4* xp = (const float4*)(x + (size_t)t * 12);
  float4 v0 = xp[0], v1 = xp[1], v2 = xp[2];
  float xv[12] = {v0.x, v0.y, v0.z, v0.w, v1.x, v1.y, v1.z, v1.w, v2.x, v2.y, v2.z, v2.w};
  const float* rp = rot + (size_t)n * 24;   // rot[n][l][m][c]
#pragma unroll
  for (int l = 0; l < LMAX; ++l) {
    float c0 = xv[2 * l], c1 = xv[2 * l + 1];
    float r00 = rp[4 * l + 0], r01 = rp[4 * l + 1];
    float r10 = rp[4 * l + 2], r11 = rp[4 * l + 3];
    float a0 = c0 * r00 + c1 * r10;   // c=0
    float a1 = c0 * r01 + c1 * r11;   // c=1
    size_t base = (size_t)l * MPAD * RIN + (size_t)(2 * n) * RIN + i;
    xr[base] = f2bf(a0);
    xr[base + RIN] = f2bf(a1);
  }
}

// ---------------------------------------------------------------------------
// K2: dual GEMM per (degree, 64-row tile), 32x32x16 MFMA, swapped operands.
// 256 thr = 4 waves. Wave w owns o-frags {2w, 2w+1} x both 32-row m-blocks
// in BOTH gemms (W1, W2 dup-free; each LDS read feeds 2 MFMAs).
// Frag addressing (verified R4-R8): row/col = lane&31, k-octet = lane>>5.
// D: col(=m)=lane&31, row(=o) = (r&3)+8*(r>>2)+4*(lane>>5).
// ---------------------------------------------------------------------------
__global__ __launch_bounds__(256, 2) void so2_gemm(
    const uint16_t* __restrict__ xr,
    const uint16_t* __restrict__ w1f,
    const uint16_t* __restrict__ w2f,
    uint16_t* __restrict__ g) {
  __shared__ alignas(16) uint8_t Xs[MTILE * 512];   // 32KB, swizzled
  __shared__ alignas(16) uint8_t A2[MTILE * 512];   // 32KB, swizzled (256-hid chunk)

  const int tile = blockIdx.x;         // same-l blocks adjacent => W hot in L2
  const int l = blockIdx.y;
  const int m0 = tile * MTILE;
  const int tid = threadIdx.x;
  const int lane = tid & 63;
  const int wid = tid >> 6;            // 0..3
  const int l31 = lane & 31;
  const int lh = lane >> 5;

  const uint16_t* w1p = w1f + (size_t)l * (RHID * RIN);
  const uint16_t* w2p = w2f + (size_t)l * (ROUT * RHID);

  // ---- stage Xr tile (64 rows x 512B) into swizzled LDS ----
  const char* xsrc = (const char*)(xr + (size_t)l * MPAD * RIN + (size_t)m0 * RIN);
#pragma unroll
  for (int it = 0; it < 8; ++it) {
    int off = it * 4096 + tid * 16;
    int row = off >> 9;
    int colb = off & 511;
    short8 v = __builtin_nontemporal_load((const short8*)(xsrc + off));
    *(short8*)(Xs + swz512(row, colb)) = v;
  }
  __syncthreads();

  f32x16 acc1[2][2];   // [fi][mb] G1 chunk accum: o-frag 2w+fi, m-block mb
  f32x16 acc2[2][2];   // [foi][mb] G2 running accum
#pragma unroll
  for (int a = 0; a < 2; ++a)
#pragma unroll
    for (int b = 0; b < 2; ++b) acc2[a][b] = (f32x16)(0.f);

  auto G1 = [&](int oc) {
#pragma unroll
    for (int a = 0; a < 2; ++a)
#pragma unroll
      for (int b = 0; b < 2; ++b) acc1[a][b] = (f32x16)(0.f);
    const uint16_t* wb0 = w1p + (size_t)(oc * 8 + wid * 2) * (16 * 64 * 8);
    const uint16_t* wb1 = wb0 + 16 * 64 * 8;
#pragma unroll 4
    for (int ks = 0; ks < 16; ++ks) {
      short8 a0 = *(const short8*)(wb0 + ((size_t)ks * 64 + lane) * 8);
      short8 a1 = *(const short8*)(wb1 + ((size_t)ks * 64 + lane) * 8);
#pragma unroll
      for (int mb = 0; mb < 2; ++mb) {
        short8 b = *(const short8*)(Xs + swz512(mb * 32 + l31, ks * 32 + lh * 16));
        acc1[0][mb] = mfma32(a0, b, acc1[0][mb]);
        acc1[1][mb] = mfma32(a1, b, acc1[1][mb]);
      }
    }
  };

  auto WA2 = [&]() {   // leaky(acc1) -> A2[m-row][chunk-local hidden col]
#pragma unroll
    for (int fi = 0; fi < 2; ++fi)
#pragma unroll
      for (int mb = 0; mb < 2; ++mb) {
        int mrow = mb * 32 + l31;
#pragma unroll
        for (int q = 0; q < 4; ++q) {
          uint2 pv;
          pv.x = cvtpk(lrelu(acc1[fi][mb][4 * q + 0]), lrelu(acc1[fi][mb][4 * q + 1]));
          pv.y = cvtpk(lrelu(acc1[fi][mb][4 * q + 2]), lrelu(acc1[fi][mb][4 * q + 3]));
          int colb = (wid * 2 + fi) * 64 + q * 16 + lh * 8;
          *(uint2*)(A2 + swz512(mrow, colb)) = pv;
        }
      }
  };

  auto G2 = [&](int oc) {   // acc2 += W2frags{2w,2w+1} x A2(both m-blocks)
#pragma unroll 4
    for (int ks = 0; ks < 16; ++ks) {
      short8 b0 = *(const short8*)(A2 + swz512(l31, ks * 32 + lh * 16));
      short8 b1 = *(const short8*)(A2 + swz512(32 + l31, ks * 32 + lh * 16));
#pragma unroll
      for (int foi = 0; foi < 2; ++foi) {
        short8 a = *(const short8*)(w2p +
            ((size_t)((wid * 2 + foi) * 32 + oc * 16 + ks) * 64 + lane) * 8);
        acc2[foi][0] = mfma32(a, b0, acc2[foi][0]);
        acc2[foi][1] = mfma32(a, b1, acc2[foi][1]);
      }
    }
  };

  // ---- schedule: 2 hidden chunks of 256, A2 single-buffered (R8-proven) ----
  G1(0);
  WA2();
  __syncthreads();

  { // fused: G2(chunk0) || G1(chunk1) — one barrier region, interleaved
#pragma unroll
    for (int a = 0; a < 2; ++a)
#pragma unroll
      for (int b = 0; b < 2; ++b) acc1[a][b] = (f32x16)(0.f);
    const uint16_t* wb0 = w1p + (size_t)(8 + wid * 2) * (16 * 64 * 8);
    const uint16_t* wb1 = wb0 + 16 * 64 * 8;
#pragma unroll 2
    for (int ks = 0; ks < 16; ++ks) {
      // G2 step (chunk 0)
      short8 b20 = *(const short8*)(A2 + swz512(l31, ks * 32 + lh * 16));
      short8 b21 = *(const short8*)(A2 + swz512(32 + l31, ks * 32 + lh * 16));
#pragma unroll
      for (int foi = 0; foi < 2; ++foi) {
        short8 a = *(const short8*)(w2p +
            ((size_t)((wid * 2 + foi) * 32 + ks) * 64 + lane) * 8);
        acc2[foi][0] = mfma32(a, b20, acc2[foi][0]);
        acc2[foi][1] = mfma32(a, b21, acc2[foi][1]);
      }
      // G1 step (chunk 1)
      short8 a10 = *(const short8*)(wb0 + ((size_t)ks * 64 + lane) * 8);
      short8 a11 = *(const short8*)(wb1 + ((size_t)ks * 64 + lane) * 8);
#pragma unroll
      for (int mb = 0; mb < 2; ++mb) {
        short8 b = *(const short8*)(Xs + swz512(mb * 32 + l31, ks * 32 + lh * 16));
        acc1[0][mb] = mfma32(a10, b, acc1[0][mb]);
        acc1[1][mb] = mfma32(a11, b, acc1[1][mb]);
      }
    }
  }
  __syncthreads();   // G2(0) done reading A2
  WA2();             // chunk-1 activations
  __syncthreads();
  G2(1);
  __syncthreads();   // A2 reads done; Xs dead

  // ---- epilogue: acc2 -> packed bf16 into Xs (swizzled) -> 16B stores ----
#pragma unroll
  for (int foi = 0; foi < 2; ++foi)
#pragma unroll
    for (int mb = 0; mb < 2; ++mb) {
      int mrow = mb * 32 + l31;
#pragma unroll
      for (int q = 0; q < 4; ++q) {
        uint2 pv;
        pv.x = cvtpk(acc2[foi][mb][4 * q + 0], acc2[foi][mb][4 * q + 1]);
        pv.y = cvtpk(acc2[foi][mb][4 * q + 2], acc2[foi][mb][4 * q + 3]);
        int colb = (wid * 2 + foi) * 64 + q * 16 + lh * 8;
        *(uint2*)(Xs + swz512(mrow, colb)) = pv;
      }
    }
  __syncthreads();

  char* gdst = (char*)(g + (size_t)l * MPAD * ROUT + (size_t)m0 * ROUT);
#pragma unroll
  for (int it = 0; it < 8; ++it) {
    int off = it * 4096 + tid * 16;
    int row = off >> 9;
    int colb = off & 511;
    short8 v = *(const short8*)(Xs + swz512(row, colb));
    __builtin_nontemporal_store(v, (short8*)(gdst + off));
  }
}

// ---------------------------------------------------------------------------
// K3: output rotation + fp32 store, fully coalesced (48 B per thread).
// out[n,o,l,m] = sum_c rot[n,l,m,c] * G[l][2n+c][o]
// ---------------------------------------------------------------------------
__global__ void post_out(const uint16_t* __restrict__ g, const float* __restrict__ rot,
                         float* __restrict__ out) {
  int n = blockIdx.x;
  int o = threadIdx.x;
  const float* rp = rot + (size_t)n * 24;
  float res[12];
#pragma unroll
  for (int l = 0; l < LMAX; ++l) {
    size_t base = (size_t)l * MPAD * ROUT + (size_t)(2 * n) * ROUT + o;
    float g0 = bf2f(g[base]);
    float g1 = bf2f(g[base + ROUT]);
    res[2 * l]     = rp[4 * l + 0] * g0 + rp[4 * l + 1] * g1;   // m=0
    res[2 * l + 1] = rp[4 * l + 2] * g0 + rp[4 * l + 3] * g1;   // m=1
  }
  float4* op = (float4*)(out + (size_t)(n * 256 + o) * 12);
  op[0] = make_float4(res[0], res[1], res[2], res[3]);
  op[1] = make_float4(res[4], res[5], res[6], res[7]);
  op[2] = make_float4(res[8], res[9], res[10], res[11]);
}

// ---------------------------------------------------------------------------
extern "C" void kernel_launch(void* const* d_in, const int* in_sizes, int n_in,
                              void* d_out, int out_size, void* d_ws, size_t ws_size,
                              hipStream_t stream) {
  (void)in_sizes; (void)n_in; (void)out_size;
  const float* x   = (const float*)d_in[0];
  const float* rot = (const float*)d_in[1];
  const float* W1  = (const float*)d_in[2];
  const float* W2  = (const float*)d_in[3];
  float* out = (float*)d_out;

  // Scratch plan:
  //   d_out (245.76 MB, overwritten by K3 at the end) doubles as scratch:
  //     [0, 123.08 MB)          Xr: 6 planes of [MPAD][RIN] bf16
  //     [123.08, 124.65 MB)     W1 bf16 fragment-linear
  //     [124.65, 126.22 MB)     W2 bf16 fragment-linear
  //   d_ws: G: 6 planes of [MPAD][ROUT] bf16 = 123,076,608 B
  const size_t xr_elems = (size_t)LMAX * MPAD * RIN;        // 61,538,304
  const size_t w_elems  = (size_t)LMAX * RHID * RIN;        // 786,432 (same W2)
  if (ws_size < (size_t)LMAX * MPAD * ROUT * 2) return;     // need 123,076,608 B

  uint16_t* xr  = (uint16_t*)d_out;
  uint16_t* w1f = xr + xr_elems;
  uint16_t* w2f = w1f + w_elems;
  uint16_t* g   = (uint16_t*)d_ws;

  prep_weights<<<3072, 256, 0, stream>>>(W1, W2, w1f, w2f);
  prep_x<<<20000, 256, 0, stream>>>(x, rot, xr);
  dim3 gg(NTILES, LMAX);   // same-l blocks adjacent: W stays hot in each L2
  so2_gemm<<<gg, 256, 0, stream>>>(xr, w1f, w2f, g);
  post_out<<<20000, 256, 0, stream>>>(g, rot, out);
}